// Round 1
// baseline (334.413 us; speedup 1.0000x reference)
//
#include <hip/hip_runtime.h>

#define G_GROUPS 512
#define CNT      8192
#define S_PAIRS  8192
#define BLOCK    1024

// Per-point LDS record: 8 fp16 = 16 B -> one ds_read_b128 per gathered point.
// [0..2] = inputs CA row, [3..5] = target CA row, [6..7] = pad.
union F4H {
    float4   f;
    _Float16 h[8];
};

__global__ __launch_bounds__(BLOCK) void rgn_loss_kernel(
    const float* __restrict__ inputs,
    const float* __restrict__ target,
    const int*   __restrict__ left,
    const int*   __restrict__ right,
    float*       __restrict__ out)
{
    __shared__ float4 pts[CNT];          // 128 KiB
    __shared__ float  red[BLOCK / 64];

    const int g   = blockIdx.x;
    const int tid = threadIdx.x;
    const int gbase = g * CNT;           // group's first global point index

    // ---- Stage this group's CA rows (row 1 of each 3x3) into LDS as fp16 ----
    for (int p = tid; p < CNT; p += BLOCK) {
        const size_t rec = (size_t)(gbase + p) * 9 + 3;   // float offset of CA row
        const float* pin = inputs + rec;
        const float* ptg = target + rec;
        F4H u;
        u.h[0] = (_Float16)pin[0];
        u.h[1] = (_Float16)pin[1];
        u.h[2] = (_Float16)pin[2];
        u.h[3] = (_Float16)ptg[0];
        u.h[4] = (_Float16)ptg[1];
        u.h[5] = (_Float16)ptg[2];
        u.h[6] = (_Float16)0.0f;
        u.h[7] = (_Float16)0.0f;
        pts[p] = u.f;
    }
    __syncthreads();

    // ---- Gather pairs, accumulate squared distance-difference ----
    const size_t pbase = (size_t)g * S_PAIRS;
    float acc = 0.0f;
    for (int k = tid; k < S_PAIRS; k += BLOCK) {
        const int li = left [pbase + k] - gbase;   // group-local by construction
        const int ri = right[pbase + k] - gbase;
        F4H L, R;
        L.f = pts[li];
        R.f = pts[ri];
        const float dix = (float)L.h[0] - (float)R.h[0];
        const float diy = (float)L.h[1] - (float)R.h[1];
        const float diz = (float)L.h[2] - (float)R.h[2];
        const float dtx = (float)L.h[3] - (float)R.h[3];
        const float dty = (float)L.h[4] - (float)R.h[4];
        const float dtz = (float)L.h[5] - (float)R.h[5];
        const float din = sqrtf(dix * dix + diy * diy + diz * diz);
        const float dtg = sqrtf(dtx * dtx + dty * dty + dtz * dtz);
        const float d   = din - dtg;
        acc += d * d;
    }

    // ---- Block reduction: wave shuffle -> LDS -> wave0 -> one atomic ----
    const int lane = tid & 63;
    const int wid  = tid >> 6;
    #pragma unroll
    for (int off = 32; off > 0; off >>= 1)
        acc += __shfl_down(acc, off);
    if (lane == 0) red[wid] = acc;
    __syncthreads();
    if (wid == 0) {
        float v = (lane < BLOCK / 64) ? red[lane] : 0.0f;
        #pragma unroll
        for (int off = 8; off > 0; off >>= 1)
            v += __shfl_down(v, off);
        if (lane == 0)
            atomicAdd(out, v * (1.0f / ((float)G_GROUPS * (float)S_PAIRS)));
    }
}

extern "C" void kernel_launch(void* const* d_in, const int* in_sizes, int n_in,
                              void* d_out, int out_size, void* d_ws, size_t ws_size,
                              hipStream_t stream) {
    const float* inputs = (const float*)d_in[0];
    const float* target = (const float*)d_in[1];
    const int*   left   = (const int*)d_in[2];
    const int*   right  = (const int*)d_in[3];
    float*       out    = (float*)d_out;

    hipMemsetAsync(out, 0, sizeof(float), stream);   // graph-capture safe
    rgn_loss_kernel<<<G_GROUPS, BLOCK, 0, stream>>>(inputs, target, left, right, out);
}